// Round 15
// baseline (141.299 us; speedup 1.0000x reference)
//
#include <hip/hip_runtime.h>

#define PAD_V 8192
#define H1 512
#define H2 64
#define B_SZ 32
#define K_SZ 32
#define L_SZ 128
#define NBAGS (B_SZ + B_SZ * K_SZ)            // 1056
#define NSLICE 8                              // codebook column slices (1 per XCD)
#define GATHER_BLOCKS (NBAGS * NSLICE)        // 8448 (pure gather)
#define MLP4_BLOCKS (NBAGS / 4)               // 264: 4 bags per block
#define ISECT2_BLOCKS ((B_SZ * K_SZ) / 2)     // 512: 2 pairs per block (in k2 grid)

// ---------------------------------------------------------------------------
// R9. Verified base (R7+R8, 139.4 us): column-sliced gather (XCD-pinned L2),
// 4-bag MLP + isect in one grid, 2-deep text_sim prefetch. Kept intact.
// R9 change (single variable): fuse text_sim + epilogue into one
// block-per-b kernel — per-pair work is ~2 dependent hit loads (nh~2), so
// both old kernels were launch-latency-bound; fusion removes one launch and
// the text ws round-trip, max done in LDS. (R0 tried this inside a bundle;
// never isolated. Now clean on a verified base.)
// NOTE (R4): no device-atomic cross-kernel fusion (+22 us). R5: no multi-bag
// in latency-bound gather. R6: gather MLP-depth is not the limiter.
// ---------------------------------------------------------------------------

// Kernel 1: pure column-sliced gather.
__global__ __launch_bounds__(256, 4) void gather_kernel(
    const int* __restrict__ qbf, const int* __restrict__ pbf,
    const float* __restrict__ codebook,
    const float* __restrict__ qa0p, const float* __restrict__ pa0p,
    float* __restrict__ x_ws)
{
    const int tid = threadIdx.x;
    const int slice = blockIdx.x & (NSLICE - 1);
    const int bag   = blockIdx.x >> 3;          // 0..1055
    const bool is_q = (bag < B_SZ);
    const int* idx_base = is_q ? qbf : pbf;
    const int  bagl     = is_q ? bag : (bag - B_SZ);
    const float a0      = is_q ? *qa0p : *pa0p;

    __shared__ int   s_idx[L_SZ];
    __shared__ int   s_cnt[2];
    __shared__ float4 s_part[16][16];           // 4 KB

    if (tid < L_SZ) {
        int v = idx_base[bagl * L_SZ + tid];
        s_idx[tid] = v;
        unsigned long long bal = __ballot(v != PAD_V);
        if ((tid & 63) == 0) s_cnt[tid >> 6] = __popcll(bal);
    }
    __syncthreads();

    // thread (r0 = tid>>4, c = tid&15): rows r0*8..r0*8+7, chunk slice*16+c.
    const int c  = tid & 15;
    const int r0 = tid >> 4;
    const int gc = slice * 16 + c;              // global float4 column 0..127
    const float4* cb4 = (const float4*)codebook;

    float ax = 0.f, ay = 0.f, az = 0.f, aw = 0.f;
    {
        int    idx[8];
        float4 buf[8];
        #pragma unroll
        for (int j = 0; j < 8; j++) idx[j] = s_idx[r0 * 8 + j];
        #pragma unroll
        for (int j = 0; j < 8; j++) buf[j] = cb4[(size_t)idx[j] * 128 + gc];
        #pragma unroll
        for (int j = 0; j < 8; j++) {
            float m = (idx[j] != PAD_V) ? 1.0f : 0.0f;
            ax = fmaf(m, buf[j].x, ax);
            ay = fmaf(m, buf[j].y, ay);
            az = fmaf(m, buf[j].z, az);
            aw = fmaf(m, buf[j].w, aw);
        }
    }
    s_part[r0][c] = make_float4(ax, ay, az, aw);
    __syncthreads();

    if (tid < 16) {
        int cnt = s_cnt[0] + s_cnt[1];
        float inv = (cnt > 0) ? 1.0f / (float)cnt : 0.0f;
        float e0 = 0.f, e1 = 0.f, e2 = 0.f, e3 = 0.f;
        #pragma unroll
        for (int r = 0; r < 16; r++) {
            float4 p = s_part[r][tid];
            e0 += p.x; e1 += p.y; e2 += p.z; e3 += p.w;
        }
        e0 *= inv; e1 *= inv; e2 *= inv; e3 *= inv;
        float4 o;
        o.x = (e0 >= 0.f) ? e0 : a0 * e0;
        o.y = (e1 >= 0.f) ? e1 : a0 * e1;
        o.z = (e2 >= 0.f) ? e2 : a0 * e2;
        o.w = (e3 >= 0.f) ? e3 : a0 * e3;
        ((float4*)x_ws)[(size_t)bag * 128 + slice * 16 + tid] = o;
    }
}

// Kernel 2: MLP (4 bags/block, weights loaded once per block) + isect role.
__global__ __launch_bounds__(256, 4) void mlp_isect_kernel(
    const float* __restrict__ x_ws,
    const int* __restrict__ qbf, const int* __restrict__ pbf,
    const float* __restrict__ qW1, const float* __restrict__ qb1,
    const float* __restrict__ qW2, const float* __restrict__ qb2,
    const float* __restrict__ pW1, const float* __restrict__ pb1,
    const float* __restrict__ pW2, const float* __restrict__ pb2,
    const float* __restrict__ qa1p, const float* __restrict__ qa2p,
    const float* __restrict__ pa1p, const float* __restrict__ pa2p,
    float* __restrict__ qh_out, float* __restrict__ ph_out,
    int* __restrict__ nh_ws, int* __restrict__ hits_ws)
{
    const int tid = threadIdx.x;

    // ---- role B: intersection (2 pairs per 256-thr block) ----
    if (blockIdx.x >= MLP4_BLOCKS) {
        __shared__ unsigned int bm2[2][256];   // 2 KB
        __shared__ int s_nh2[2];
        __shared__ int s_hit2[2][L_SZ];        // 1 KB

        const int pair0 = (blockIdx.x - MLP4_BLOCKS) * 2;
        const int sub = tid >> 7;              // 0..1
        const int t   = tid & 127;
        const int pair = pair0 + sub;
        const int b = pair >> 5;

        bm2[sub][t] = 0u; bm2[sub][t + 128] = 0u;
        if (t == 0) s_nh2[sub] = 0;
        __syncthreads();

        int pv = pbf[pair * L_SZ + t];
        if ((unsigned)pv < (unsigned)PAD_V)
            atomicOr(&bm2[sub][pv >> 5], 1u << (pv & 31));
        __syncthreads();

        int v = qbf[b * L_SZ + t];
        bool hit = ((unsigned)v < (unsigned)PAD_V) &&
                   ((bm2[sub][v >> 5] >> (v & 31)) & 1u);
        if (hit) {
            int pos = atomicAdd(&s_nh2[sub], 1);
            s_hit2[sub][pos] = v;
        }
        __syncthreads();

        if (t == 0) nh_ws[pair] = s_nh2[sub];
        if (t < s_nh2[sub]) hits_ws[pair * L_SZ + t] = s_hit2[sub][t];
        return;
    }

    // ---- role A: MLP, 4 bags per block (all same type: q blocks 0..7) ----
    const int m = blockIdx.x;
    const bool is_q = (m < (B_SZ / 4));
    const int bag0 = m * 4;                    // global bag 4m..4m+3
    const float *W1, *b1, *W2, *b2;
    float a1, a2;
    float* out;
    int bagl0;
    if (is_q) {
        bagl0 = bag0;
        W1 = qW1; b1 = qb1; W2 = qW2; b2 = qb2;
        a1 = *qa1p; a2 = *qa2p;
        out = qh_out;
    } else {
        bagl0 = bag0 - B_SZ;
        W1 = pW1; b1 = pb1; W2 = pW2; b2 = pb2;
        a1 = *pa1p; a2 = *pa2p;
        out = ph_out;
    }

    __shared__ float s_x[4][H1];       // 8 KB
    __shared__ float s_p1[4][16][H2];  // 16 KB
    __shared__ float s_h1[4][H2];      // 1 KB

    {
        const float4* x4 = (const float4*)x_ws;
        float4* sx4 = (float4*)&s_x[0][0];
        sx4[tid]       = x4[(size_t)bag0 * 128 + tid];
        sx4[tid + 256] = x4[(size_t)bag0 * 128 + tid + 256];
    }
    __syncthreads();

    const int j4 = tid & 15;   // col quad
    const int ch = tid >> 4;   // 0..15 i-chunk

    // layer 1: 32 i's per chunk; each weight float4 applied to 4 bags
    {
        const float4* W1v = (const float4*)W1;
        const int i0 = ch * 32;
        float4 A0 = make_float4(0.f,0.f,0.f,0.f);
        float4 A1 = make_float4(0.f,0.f,0.f,0.f);
        float4 A2 = make_float4(0.f,0.f,0.f,0.f);
        float4 A3 = make_float4(0.f,0.f,0.f,0.f);
        #pragma unroll 8
        for (int i = 0; i < 32; i++) {
            float4 w = W1v[(size_t)(i0 + i) * 16 + j4];
            float x0 = s_x[0][i0 + i];
            float x1 = s_x[1][i0 + i];
            float x2 = s_x[2][i0 + i];
            float x3 = s_x[3][i0 + i];
            A0.x = fmaf(x0, w.x, A0.x); A0.y = fmaf(x0, w.y, A0.y);
            A0.z = fmaf(x0, w.z, A0.z); A0.w = fmaf(x0, w.w, A0.w);
            A1.x = fmaf(x1, w.x, A1.x); A1.y = fmaf(x1, w.y, A1.y);
            A1.z = fmaf(x1, w.z, A1.z); A1.w = fmaf(x1, w.w, A1.w);
            A2.x = fmaf(x2, w.x, A2.x); A2.y = fmaf(x2, w.y, A2.y);
            A2.z = fmaf(x2, w.z, A2.z); A2.w = fmaf(x2, w.w, A2.w);
            A3.x = fmaf(x3, w.x, A3.x); A3.y = fmaf(x3, w.y, A3.y);
            A3.z = fmaf(x3, w.z, A3.z); A3.w = fmaf(x3, w.w, A3.w);
        }
        s_p1[0][ch][4*j4+0] = A0.x; s_p1[0][ch][4*j4+1] = A0.y;
        s_p1[0][ch][4*j4+2] = A0.z; s_p1[0][ch][4*j4+3] = A0.w;
        s_p1[1][ch][4*j4+0] = A1.x; s_p1[1][ch][4*j4+1] = A1.y;
        s_p1[1][ch][4*j4+2] = A1.z; s_p1[1][ch][4*j4+3] = A1.w;
        s_p1[2][ch][4*j4+0] = A2.x; s_p1[2][ch][4*j4+1] = A2.y;
        s_p1[2][ch][4*j4+2] = A2.z; s_p1[2][ch][4*j4+3] = A2.w;
        s_p1[3][ch][4*j4+0] = A3.x; s_p1[3][ch][4*j4+1] = A3.y;
        s_p1[3][ch][4*j4+2] = A3.z; s_p1[3][ch][4*j4+3] = A3.w;
    }
    __syncthreads();
    {
        const int bg = tid >> 6, col = tid & 63;   // 4 bags x 64 cols = 256
        float s = b1[col];
        #pragma unroll
        for (int r = 0; r < 16; r++) s += s_p1[bg][r][col];
        s_h1[bg][col] = (s >= 0.f) ? s : a1 * s;
    }
    __syncthreads();

    // layer 2: 4 i's per chunk
    {
        const float4* W2v = (const float4*)W2;
        const int i0 = ch * 4;
        float4 A0 = make_float4(0.f,0.f,0.f,0.f);
        float4 A1 = make_float4(0.f,0.f,0.f,0.f);
        float4 A2 = make_float4(0.f,0.f,0.f,0.f);
        float4 A3 = make_float4(0.f,0.f,0.f,0.f);
        #pragma unroll
        for (int i = 0; i < 4; i++) {
            float4 w = W2v[(size_t)(i0 + i) * 16 + j4];
            float x0 = s_h1[0][i0 + i];
            float x1 = s_h1[1][i0 + i];
            float x2 = s_h1[2][i0 + i];
            float x3 = s_h1[3][i0 + i];
            A0.x = fmaf(x0, w.x, A0.x); A0.y = fmaf(x0, w.y, A0.y);
            A0.z = fmaf(x0, w.z, A0.z); A0.w = fmaf(x0, w.w, A0.w);
            A1.x = fmaf(x1, w.x, A1.x); A1.y = fmaf(x1, w.y, A1.y);
            A1.z = fmaf(x1, w.z, A1.z); A1.w = fmaf(x1, w.w, A1.w);
            A2.x = fmaf(x2, w.x, A2.x); A2.y = fmaf(x2, w.y, A2.y);
            A2.z = fmaf(x2, w.z, A2.z); A2.w = fmaf(x2, w.w, A2.w);
            A3.x = fmaf(x3, w.x, A3.x); A3.y = fmaf(x3, w.y, A3.y);
            A3.z = fmaf(x3, w.z, A3.z); A3.w = fmaf(x3, w.w, A3.w);
        }
        s_p1[0][ch][4*j4+0] = A0.x; s_p1[0][ch][4*j4+1] = A0.y;
        s_p1[0][ch][4*j4+2] = A0.z; s_p1[0][ch][4*j4+3] = A0.w;
        s_p1[1][ch][4*j4+0] = A1.x; s_p1[1][ch][4*j4+1] = A1.y;
        s_p1[1][ch][4*j4+2] = A1.z; s_p1[1][ch][4*j4+3] = A1.w;
        s_p1[2][ch][4*j4+0] = A2.x; s_p1[2][ch][4*j4+1] = A2.y;
        s_p1[2][ch][4*j4+2] = A2.z; s_p1[2][ch][4*j4+3] = A2.w;
        s_p1[3][ch][4*j4+0] = A3.x; s_p1[3][ch][4*j4+1] = A3.y;
        s_p1[3][ch][4*j4+2] = A3.z; s_p1[3][ch][4*j4+3] = A3.w;
    }
    __syncthreads();
    {
        const int bg = tid >> 6, col = tid & 63;
        float s = b2[col];
        #pragma unroll
        for (int r = 0; r < 16; r++) s += s_p1[bg][r][col];
        s = (s >= 0.f) ? s : a2 * s;
        out[(bagl0 + bg) * H2 + col] = s;
    }
}

// ---------------------------------------------------------------------------
// Kernel 3 (fused): text-sim dots (2-deep prefetch) + max + sigmoid +
// distance epilogue. One block per b; wave w handles pairs w and w+16.
// ---------------------------------------------------------------------------
__global__ __launch_bounds__(1024) void sim_epilogue_kernel(
    const float* __restrict__ q_eval, const float* __restrict__ p_eval,
    const float* __restrict__ qh_ws, const float* __restrict__ ph_ws,
    const int* __restrict__ nh_ws, const int* __restrict__ hits_ws,
    const float* __restrict__ ind_ap,
    const float* __restrict__ qloc, const float* __restrict__ ploc,
    const float* __restrict__ ap, const float* __restrict__ bp,
    const float* __restrict__ cp, const float* __restrict__ dp,
    float* __restrict__ out)
{
    const int b    = blockIdx.x;
    const int tid  = threadIdx.x;
    const int wave = tid >> 6;
    const int lane = tid & 63;
    __shared__ float s_text[K_SZ];

    const float ind_a = *ind_ap;
    const float qh = qh_ws[b * H2 + lane];   // same for every k of this b

    for (int kk = wave; kk < K_SZ; kk += 16) {
        const int blk = b * K_SZ + kk;
        const float ph = ph_ws[blk * H2 + lane];
        const int   nh = nh_ws[blk];
        float local = 0.f;
        if (nh > 0) {
            int v = hits_ws[blk * L_SZ];
            float qe = q_eval[(size_t)v * H2 + lane];
            float pe = p_eval[(size_t)v * H2 + lane];
            for (int hh = 0; hh < nh; hh++) {
                float qe_n = 0.f, pe_n = 0.f;
                if (hh + 1 < nh) {                // uniform branch per wave
                    int vn = hits_ws[blk * L_SZ + hh + 1];
                    qe_n = q_eval[(size_t)vn * H2 + lane];
                    pe_n = p_eval[(size_t)vn * H2 + lane];
                }
                float qd = qh * qe;
                float pd = ph * pe;
                #pragma unroll
                for (int m = 1; m < 64; m <<= 1) {
                    qd += __shfl_xor(qd, m);
                    pd += __shfl_xor(pd, m);
                }
                qd = (qd >= 0.f) ? qd : ind_a * qd;
                pd = (pd >= 0.f) ? pd : ind_a * pd;
                local += (qd + 1.f) * (pd + 1.f);
                qe = qe_n; pe = pe_n;
            }
        }
        if (lane == 0) s_text[kk] = local;
    }
    __syncthreads();

    if (tid < K_SZ) {
        const int kk = tid;
        float ts_raw = s_text[kk];
        float mx = ts_raw;
        #pragma unroll
        for (int m = 1; m < 32; m <<= 1) mx = fmaxf(mx, __shfl_xor(mx, m));

        float qx = qloc[b * 2], qy = qloc[b * 2 + 1];
        float px = ploc[(b * K_SZ + kk) * 2];
        float py = ploc[(b * K_SZ + kk) * 2 + 1];
        float dx = qx - px, dy = qy - py;
        float dist = sqrtf(dx * dx + dy * dy);
        float ds = -logf(dist + 1.0f);

        float ts = (2.0f * ts_raw - mx) / (mx + 1e-6f);
        float A = *ap, Bb = *bp, C = *cp, D = *dp;
        float sig = 1.0f / (1.0f + expf(-(A * ts + Bb)));
        out[b * K_SZ + kk] = (C - sig) * (ds - D);
    }
}

extern "C" void kernel_launch(void* const* d_in, const int* in_sizes, int n_in,
                              void* d_out, int out_size, void* d_ws, size_t ws_size,
                              hipStream_t stream) {
    const int*   qbf      = (const int*)d_in[0];
    const int*   pbf      = (const int*)d_in[1];
    const float* qloc     = (const float*)d_in[2];
    const float* ploc     = (const float*)d_in[3];
    const float* codebook = (const float*)d_in[4];
    const float* qW1      = (const float*)d_in[5];
    const float* qb1      = (const float*)d_in[6];
    const float* qW2      = (const float*)d_in[7];
    const float* qb2      = (const float*)d_in[8];
    const float* pW1      = (const float*)d_in[9];
    const float* pb1      = (const float*)d_in[10];
    const float* pW2      = (const float*)d_in[11];
    const float* pb2      = (const float*)d_in[12];
    const float* q_eval   = (const float*)d_in[13];
    const float* p_eval   = (const float*)d_in[14];
    const float* qa0      = (const float*)d_in[15];
    const float* qa1      = (const float*)d_in[16];
    const float* qa2      = (const float*)d_in[17];
    const float* pa0      = (const float*)d_in[18];
    const float* pa1      = (const float*)d_in[19];
    const float* pa2      = (const float*)d_in[20];
    const float* ind_a    = (const float*)d_in[21];
    const float* a        = (const float*)d_in[22];
    const float* bsc      = (const float*)d_in[23];
    const float* c        = (const float*)d_in[24];
    const float* d        = (const float*)d_in[25];

    float* qh   = (float*)d_ws;                   // 32*64
    float* ph   = qh + B_SZ * H2;                 // 1024*64
    int*   nh   = (int*)(ph + B_SZ * K_SZ * H2);  // 1024
    int*   hits = nh + B_SZ * K_SZ;               // 1024*128
    float* x_ws = (float*)(hits + B_SZ * K_SZ * L_SZ);  // 1056*512 (16B-aligned)

    gather_kernel<<<GATHER_BLOCKS, 256, 0, stream>>>(
        qbf, pbf, codebook, qa0, pa0, x_ws);

    mlp_isect_kernel<<<MLP4_BLOCKS + ISECT2_BLOCKS, 256, 0, stream>>>(
        x_ws, qbf, pbf,
        qW1, qb1, qW2, qb2, pW1, pb1, pW2, pb2,
        qa1, qa2, pa1, pa2, qh, ph, nh, hits);

    sim_epilogue_kernel<<<B_SZ, 1024, 0, stream>>>(
        q_eval, p_eval, qh, ph, nh, hits, ind_a,
        qloc, ploc, a, bsc, c, d, (float*)d_out);
}

// Round 16
// 139.355 us; speedup vs baseline: 1.0140x; 1.0140x over previous
//
#include <hip/hip_runtime.h>

#define PAD_V 8192
#define H1 512
#define H2 64
#define B_SZ 32
#define K_SZ 32
#define L_SZ 128
#define NBAGS (B_SZ + B_SZ * K_SZ)            // 1056
#define NSLICE 8                              // codebook column slices (1 per XCD)
#define GATHER_BLOCKS (NBAGS * NSLICE)        // 8448 (pure gather)
#define MLP4_BLOCKS (NBAGS / 4)               // 264: 4 bags per block
#define ISECT2_BLOCKS ((B_SZ * K_SZ) / 2)     // 512: 2 pairs per block (in k2 grid)

// ---------------------------------------------------------------------------
// R10 = revert to R8 (verified 139.4 us best). R9 post-mortem: tail fusion
// was neutral-to-negative (+1.9 us despite faster fills) — the unfused
// epilogue already rode in launch-pipeline slack; fusion serialized 32
// k-dots per block + added a barrier. Keeping the 4-launch structure.
// Verified structure: column-sliced gather (slice = blockIdx%8 pins each
// XCD L2 to a 2.1MB codebook column set; R7 -12us), 4-bag MLP + isect in
// one grid (R8 -6us), 2-deep text_sim prefetch.
// NOTE (R4): no device-atomic cross-kernel fusion (+22 us). R5: no multi-bag
// in latency-bound gather. R6: gather MLP-depth is not the limiter.
// R9: no tail fusion.
// ---------------------------------------------------------------------------

// Kernel 1: pure column-sliced gather.
__global__ __launch_bounds__(256, 4) void gather_kernel(
    const int* __restrict__ qbf, const int* __restrict__ pbf,
    const float* __restrict__ codebook,
    const float* __restrict__ qa0p, const float* __restrict__ pa0p,
    float* __restrict__ x_ws)
{
    const int tid = threadIdx.x;
    const int slice = blockIdx.x & (NSLICE - 1);
    const int bag   = blockIdx.x >> 3;          // 0..1055
    const bool is_q = (bag < B_SZ);
    const int* idx_base = is_q ? qbf : pbf;
    const int  bagl     = is_q ? bag : (bag - B_SZ);
    const float a0      = is_q ? *qa0p : *pa0p;

    __shared__ int   s_idx[L_SZ];
    __shared__ int   s_cnt[2];
    __shared__ float4 s_part[16][16];           // 4 KB

    if (tid < L_SZ) {
        int v = idx_base[bagl * L_SZ + tid];
        s_idx[tid] = v;
        unsigned long long bal = __ballot(v != PAD_V);
        if ((tid & 63) == 0) s_cnt[tid >> 6] = __popcll(bal);
    }
    __syncthreads();

    // thread (r0 = tid>>4, c = tid&15): rows r0*8..r0*8+7, chunk slice*16+c.
    const int c  = tid & 15;
    const int r0 = tid >> 4;
    const int gc = slice * 16 + c;              // global float4 column 0..127
    const float4* cb4 = (const float4*)codebook;

    float ax = 0.f, ay = 0.f, az = 0.f, aw = 0.f;
    {
        int    idx[8];
        float4 buf[8];
        #pragma unroll
        for (int j = 0; j < 8; j++) idx[j] = s_idx[r0 * 8 + j];
        #pragma unroll
        for (int j = 0; j < 8; j++) buf[j] = cb4[(size_t)idx[j] * 128 + gc];
        #pragma unroll
        for (int j = 0; j < 8; j++) {
            float m = (idx[j] != PAD_V) ? 1.0f : 0.0f;
            ax = fmaf(m, buf[j].x, ax);
            ay = fmaf(m, buf[j].y, ay);
            az = fmaf(m, buf[j].z, az);
            aw = fmaf(m, buf[j].w, aw);
        }
    }
    s_part[r0][c] = make_float4(ax, ay, az, aw);
    __syncthreads();

    if (tid < 16) {
        int cnt = s_cnt[0] + s_cnt[1];
        float inv = (cnt > 0) ? 1.0f / (float)cnt : 0.0f;
        float e0 = 0.f, e1 = 0.f, e2 = 0.f, e3 = 0.f;
        #pragma unroll
        for (int r = 0; r < 16; r++) {
            float4 p = s_part[r][tid];
            e0 += p.x; e1 += p.y; e2 += p.z; e3 += p.w;
        }
        e0 *= inv; e1 *= inv; e2 *= inv; e3 *= inv;
        float4 o;
        o.x = (e0 >= 0.f) ? e0 : a0 * e0;
        o.y = (e1 >= 0.f) ? e1 : a0 * e1;
        o.z = (e2 >= 0.f) ? e2 : a0 * e2;
        o.w = (e3 >= 0.f) ? e3 : a0 * e3;
        ((float4*)x_ws)[(size_t)bag * 128 + slice * 16 + tid] = o;
    }
}

// Kernel 2: MLP (4 bags/block, weights loaded once per block) + isect role.
__global__ __launch_bounds__(256, 4) void mlp_isect_kernel(
    const float* __restrict__ x_ws,
    const int* __restrict__ qbf, const int* __restrict__ pbf,
    const float* __restrict__ qW1, const float* __restrict__ qb1,
    const float* __restrict__ qW2, const float* __restrict__ qb2,
    const float* __restrict__ pW1, const float* __restrict__ pb1,
    const float* __restrict__ pW2, const float* __restrict__ pb2,
    const float* __restrict__ qa1p, const float* __restrict__ qa2p,
    const float* __restrict__ pa1p, const float* __restrict__ pa2p,
    float* __restrict__ qh_out, float* __restrict__ ph_out,
    int* __restrict__ nh_ws, int* __restrict__ hits_ws)
{
    const int tid = threadIdx.x;

    // ---- role B: intersection (2 pairs per 256-thr block) ----
    if (blockIdx.x >= MLP4_BLOCKS) {
        __shared__ unsigned int bm2[2][256];   // 2 KB
        __shared__ int s_nh2[2];
        __shared__ int s_hit2[2][L_SZ];        // 1 KB

        const int pair0 = (blockIdx.x - MLP4_BLOCKS) * 2;
        const int sub = tid >> 7;              // 0..1
        const int t   = tid & 127;
        const int pair = pair0 + sub;
        const int b = pair >> 5;

        bm2[sub][t] = 0u; bm2[sub][t + 128] = 0u;
        if (t == 0) s_nh2[sub] = 0;
        __syncthreads();

        int pv = pbf[pair * L_SZ + t];
        if ((unsigned)pv < (unsigned)PAD_V)
            atomicOr(&bm2[sub][pv >> 5], 1u << (pv & 31));
        __syncthreads();

        int v = qbf[b * L_SZ + t];
        bool hit = ((unsigned)v < (unsigned)PAD_V) &&
                   ((bm2[sub][v >> 5] >> (v & 31)) & 1u);
        if (hit) {
            int pos = atomicAdd(&s_nh2[sub], 1);
            s_hit2[sub][pos] = v;
        }
        __syncthreads();

        if (t == 0) nh_ws[pair] = s_nh2[sub];
        if (t < s_nh2[sub]) hits_ws[pair * L_SZ + t] = s_hit2[sub][t];
        return;
    }

    // ---- role A: MLP, 4 bags per block (all same type: q blocks 0..7) ----
    const int m = blockIdx.x;
    const bool is_q = (m < (B_SZ / 4));
    const int bag0 = m * 4;                    // global bag 4m..4m+3
    const float *W1, *b1, *W2, *b2;
    float a1, a2;
    float* out;
    int bagl0;
    if (is_q) {
        bagl0 = bag0;
        W1 = qW1; b1 = qb1; W2 = qW2; b2 = qb2;
        a1 = *qa1p; a2 = *qa2p;
        out = qh_out;
    } else {
        bagl0 = bag0 - B_SZ;
        W1 = pW1; b1 = pb1; W2 = pW2; b2 = pb2;
        a1 = *pa1p; a2 = *pa2p;
        out = ph_out;
    }

    __shared__ float s_x[4][H1];       // 8 KB
    __shared__ float s_p1[4][16][H2];  // 16 KB
    __shared__ float s_h1[4][H2];      // 1 KB

    {
        const float4* x4 = (const float4*)x_ws;
        float4* sx4 = (float4*)&s_x[0][0];
        sx4[tid]       = x4[(size_t)bag0 * 128 + tid];
        sx4[tid + 256] = x4[(size_t)bag0 * 128 + tid + 256];
    }
    __syncthreads();

    const int j4 = tid & 15;   // col quad
    const int ch = tid >> 4;   // 0..15 i-chunk

    // layer 1: 32 i's per chunk; each weight float4 applied to 4 bags
    {
        const float4* W1v = (const float4*)W1;
        const int i0 = ch * 32;
        float4 A0 = make_float4(0.f,0.f,0.f,0.f);
        float4 A1 = make_float4(0.f,0.f,0.f,0.f);
        float4 A2 = make_float4(0.f,0.f,0.f,0.f);
        float4 A3 = make_float4(0.f,0.f,0.f,0.f);
        #pragma unroll 8
        for (int i = 0; i < 32; i++) {
            float4 w = W1v[(size_t)(i0 + i) * 16 + j4];
            float x0 = s_x[0][i0 + i];
            float x1 = s_x[1][i0 + i];
            float x2 = s_x[2][i0 + i];
            float x3 = s_x[3][i0 + i];
            A0.x = fmaf(x0, w.x, A0.x); A0.y = fmaf(x0, w.y, A0.y);
            A0.z = fmaf(x0, w.z, A0.z); A0.w = fmaf(x0, w.w, A0.w);
            A1.x = fmaf(x1, w.x, A1.x); A1.y = fmaf(x1, w.y, A1.y);
            A1.z = fmaf(x1, w.z, A1.z); A1.w = fmaf(x1, w.w, A1.w);
            A2.x = fmaf(x2, w.x, A2.x); A2.y = fmaf(x2, w.y, A2.y);
            A2.z = fmaf(x2, w.z, A2.z); A2.w = fmaf(x2, w.w, A2.w);
            A3.x = fmaf(x3, w.x, A3.x); A3.y = fmaf(x3, w.y, A3.y);
            A3.z = fmaf(x3, w.z, A3.z); A3.w = fmaf(x3, w.w, A3.w);
        }
        s_p1[0][ch][4*j4+0] = A0.x; s_p1[0][ch][4*j4+1] = A0.y;
        s_p1[0][ch][4*j4+2] = A0.z; s_p1[0][ch][4*j4+3] = A0.w;
        s_p1[1][ch][4*j4+0] = A1.x; s_p1[1][ch][4*j4+1] = A1.y;
        s_p1[1][ch][4*j4+2] = A1.z; s_p1[1][ch][4*j4+3] = A1.w;
        s_p1[2][ch][4*j4+0] = A2.x; s_p1[2][ch][4*j4+1] = A2.y;
        s_p1[2][ch][4*j4+2] = A2.z; s_p1[2][ch][4*j4+3] = A2.w;
        s_p1[3][ch][4*j4+0] = A3.x; s_p1[3][ch][4*j4+1] = A3.y;
        s_p1[3][ch][4*j4+2] = A3.z; s_p1[3][ch][4*j4+3] = A3.w;
    }
    __syncthreads();
    {
        const int bg = tid >> 6, col = tid & 63;   // 4 bags x 64 cols = 256
        float s = b1[col];
        #pragma unroll
        for (int r = 0; r < 16; r++) s += s_p1[bg][r][col];
        s_h1[bg][col] = (s >= 0.f) ? s : a1 * s;
    }
    __syncthreads();

    // layer 2: 4 i's per chunk
    {
        const float4* W2v = (const float4*)W2;
        const int i0 = ch * 4;
        float4 A0 = make_float4(0.f,0.f,0.f,0.f);
        float4 A1 = make_float4(0.f,0.f,0.f,0.f);
        float4 A2 = make_float4(0.f,0.f,0.f,0.f);
        float4 A3 = make_float4(0.f,0.f,0.f,0.f);
        #pragma unroll
        for (int i = 0; i < 4; i++) {
            float4 w = W2v[(size_t)(i0 + i) * 16 + j4];
            float x0 = s_h1[0][i0 + i];
            float x1 = s_h1[1][i0 + i];
            float x2 = s_h1[2][i0 + i];
            float x3 = s_h1[3][i0 + i];
            A0.x = fmaf(x0, w.x, A0.x); A0.y = fmaf(x0, w.y, A0.y);
            A0.z = fmaf(x0, w.z, A0.z); A0.w = fmaf(x0, w.w, A0.w);
            A1.x = fmaf(x1, w.x, A1.x); A1.y = fmaf(x1, w.y, A1.y);
            A1.z = fmaf(x1, w.z, A1.z); A1.w = fmaf(x1, w.w, A1.w);
            A2.x = fmaf(x2, w.x, A2.x); A2.y = fmaf(x2, w.y, A2.y);
            A2.z = fmaf(x2, w.z, A2.z); A2.w = fmaf(x2, w.w, A2.w);
            A3.x = fmaf(x3, w.x, A3.x); A3.y = fmaf(x3, w.y, A3.y);
            A3.z = fmaf(x3, w.z, A3.z); A3.w = fmaf(x3, w.w, A3.w);
        }
        s_p1[0][ch][4*j4+0] = A0.x; s_p1[0][ch][4*j4+1] = A0.y;
        s_p1[0][ch][4*j4+2] = A0.z; s_p1[0][ch][4*j4+3] = A0.w;
        s_p1[1][ch][4*j4+0] = A1.x; s_p1[1][ch][4*j4+1] = A1.y;
        s_p1[1][ch][4*j4+2] = A1.z; s_p1[1][ch][4*j4+3] = A1.w;
        s_p1[2][ch][4*j4+0] = A2.x; s_p1[2][ch][4*j4+1] = A2.y;
        s_p1[2][ch][4*j4+2] = A2.z; s_p1[2][ch][4*j4+3] = A2.w;
        s_p1[3][ch][4*j4+0] = A3.x; s_p1[3][ch][4*j4+1] = A3.y;
        s_p1[3][ch][4*j4+2] = A3.z; s_p1[3][ch][4*j4+3] = A3.w;
    }
    __syncthreads();
    {
        const int bg = tid >> 6, col = tid & 63;
        float s = b2[col];
        #pragma unroll
        for (int r = 0; r < 16; r++) s += s_p1[bg][r][col];
        s = (s >= 0.f) ? s : a2 * s;
        out[(bagl0 + bg) * H2 + col] = s;
    }
}

// ---------------------------------------------------------------------------
// Kernel 3: one wave per (b,k), 2-deep prefetch over precompacted hits.
// ---------------------------------------------------------------------------
__global__ __launch_bounds__(64) void text_sim_kernel(
    const float* __restrict__ q_eval, const float* __restrict__ p_eval,
    const float* __restrict__ qh_ws, const float* __restrict__ ph_ws,
    const int* __restrict__ nh_ws, const int* __restrict__ hits_ws,
    const float* __restrict__ ind_ap,
    float* __restrict__ text_out)
{
    const int blk = blockIdx.x;      // (b,k) pair
    const int b    = blk >> 5;
    const int lane = threadIdx.x;    // 0..63

    const float qh = qh_ws[b * H2 + lane];
    const float ph = ph_ws[blk * H2 + lane];
    const int   nh = nh_ws[blk];
    const float ind_a = *ind_ap;

    float local = 0.f;
    if (nh > 0) {
        int v = hits_ws[blk * L_SZ];
        float qe = q_eval[(size_t)v * H2 + lane];
        float pe = p_eval[(size_t)v * H2 + lane];
        for (int hh = 0; hh < nh; hh++) {
            float qe_n = 0.f, pe_n = 0.f;
            if (hh + 1 < nh) {                    // uniform branch per wave
                int vn = hits_ws[blk * L_SZ + hh + 1];
                qe_n = q_eval[(size_t)vn * H2 + lane];
                pe_n = p_eval[(size_t)vn * H2 + lane];
            }
            float qd = qh * qe;
            float pd = ph * pe;
            #pragma unroll
            for (int m = 1; m < 64; m <<= 1) {
                qd += __shfl_xor(qd, m);
                pd += __shfl_xor(pd, m);
            }
            qd = (qd >= 0.f) ? qd : ind_a * qd;
            pd = (pd >= 0.f) ? pd : ind_a * pd;
            local += (qd + 1.f) * (pd + 1.f);
            qe = qe_n; pe = pe_n;
        }
    }
    if (lane == 0) text_out[blk] = local;
}

// ---------------------------------------------------------------------------
// Kernel 4: epilogue — one block per b: max, normalize, sigmoid, distance.
// ---------------------------------------------------------------------------
__global__ __launch_bounds__(64) void epilogue_kernel(
    const float* __restrict__ text_ws,
    const float* __restrict__ qloc, const float* __restrict__ ploc,
    const float* __restrict__ ap, const float* __restrict__ bp,
    const float* __restrict__ cp, const float* __restrict__ dp,
    float* __restrict__ out)
{
    const int b = blockIdx.x;
    const int t = threadIdx.x;
    const int kk = t & 31;

    float ts_raw = text_ws[b * K_SZ + kk];
    float mx = ts_raw;
    #pragma unroll
    for (int m = 1; m < 32; m <<= 1) mx = fmaxf(mx, __shfl_xor(mx, m));

    float qx = qloc[b * 2], qy = qloc[b * 2 + 1];
    float px = ploc[(b * K_SZ + kk) * 2];
    float py = ploc[(b * K_SZ + kk) * 2 + 1];
    float dx = qx - px, dy = qy - py;
    float dist = sqrtf(dx * dx + dy * dy);
    float ds = -logf(dist + 1.0f);

    float ts = (2.0f * ts_raw - mx) / (mx + 1e-6f);
    float A = *ap, Bb = *bp, C = *cp, D = *dp;
    float sig = 1.0f / (1.0f + expf(-(A * ts + Bb)));
    if (t < 32) out[b * K_SZ + kk] = (C - sig) * (ds - D);
}

extern "C" void kernel_launch(void* const* d_in, const int* in_sizes, int n_in,
                              void* d_out, int out_size, void* d_ws, size_t ws_size,
                              hipStream_t stream) {
    const int*   qbf      = (const int*)d_in[0];
    const int*   pbf      = (const int*)d_in[1];
    const float* qloc     = (const float*)d_in[2];
    const float* ploc     = (const float*)d_in[3];
    const float* codebook = (const float*)d_in[4];
    const float* qW1      = (const float*)d_in[5];
    const float* qb1      = (const float*)d_in[6];
    const float* qW2      = (const float*)d_in[7];
    const float* qb2      = (const float*)d_in[8];
    const float* pW1      = (const float*)d_in[9];
    const float* pb1      = (const float*)d_in[10];
    const float* pW2      = (const float*)d_in[11];
    const float* pb2      = (const float*)d_in[12];
    const float* q_eval   = (const float*)d_in[13];
    const float* p_eval   = (const float*)d_in[14];
    const float* qa0      = (const float*)d_in[15];
    const float* qa1      = (const float*)d_in[16];
    const float* qa2      = (const float*)d_in[17];
    const float* pa0      = (const float*)d_in[18];
    const float* pa1      = (const float*)d_in[19];
    const float* pa2      = (const float*)d_in[20];
    const float* ind_a    = (const float*)d_in[21];
    const float* a        = (const float*)d_in[22];
    const float* bsc      = (const float*)d_in[23];
    const float* c        = (const float*)d_in[24];
    const float* d        = (const float*)d_in[25];

    float* qh   = (float*)d_ws;                   // 32*64
    float* ph   = qh + B_SZ * H2;                 // 1024*64
    float* text = ph + B_SZ * K_SZ * H2;          // 1024
    int*   nh   = (int*)(text + B_SZ * K_SZ);     // 1024
    int*   hits = nh + B_SZ * K_SZ;               // 1024*128
    float* x_ws = (float*)(hits + B_SZ * K_SZ * L_SZ);  // 1056*512 (16B-aligned)

    gather_kernel<<<GATHER_BLOCKS, 256, 0, stream>>>(
        qbf, pbf, codebook, qa0, pa0, x_ws);

    mlp_isect_kernel<<<MLP4_BLOCKS + ISECT2_BLOCKS, 256, 0, stream>>>(
        x_ws, qbf, pbf,
        qW1, qb1, qW2, qb2, pW1, pb1, pW2, pb2,
        qa1, qa2, pa1, pa2, qh, ph, nh, hits);

    text_sim_kernel<<<B_SZ * K_SZ, 64, 0, stream>>>(
        q_eval, p_eval, qh, ph, nh, hits, ind_a, text);

    epilogue_kernel<<<B_SZ, 64, 0, stream>>>(
        text, qloc, ploc, a, bsc, c, d, (float*)d_out);
}